// Round 17
// baseline (3469.257 us; speedup 1.0000x reference)
//
#include <hip/hip_runtime.h>
#include <hip/hip_bf16.h>

// SentenceClassifier: LSTM(B=64,T=512,E=512,H=1024) -> h_T @ outW + outb -> softmax/CE
// Persistent-kernel, 128 worker blocks x 256 thr + 2 aggregator blocks.
// R17 = R16 (best, 2717us) + GROUP-GRANULAR EPOCHS: each aggregator publishes
// 8 group-epochs per plane (min over 16 producer flags, 8-lane shfl-min
// subgroups) instead of one full-min epoch. Consumers software-pipeline:
// check(g) -> issue polls(g+1) -> issue loads(g) -> MFMA(g-1). Poll loads are
// issued BEFORE the group's h-loads, so the compiler's in-order counted vmcnt
// retires polls while h-loads stay in flight (no manual drains in the h-GEMM).
// Group 0's wait sees max-of-16 skew (not max-of-128); stragglers in later
// groups absorb under MFMA+load overlap. Accumulation order identical to R16
// (groups 0-3 -> a-chains, 4-7 -> b-chains): bit-identical numerics.
// Tail R16-verbatim: inline cell pack+store (8B agent write-through), counted
// store-ack vmcnt(16) overlapped with t+1 x-loads, flag store, x-GEMM in
// detect shadow, x-part W in registers, no __syncthreads in t-loop.

#define Bb 64
#define Tt 512
#define Ee 512
#define Hh 1024
#define Cc 32
#define G4 4096
#define NKS 48     // (E+H)/32
#define NBLK 128
#define HIDB 8     // hid units per block
#define FPAD 32    // flag slot pad (ints) = 128B
#define NREP 16    // epoch lines per plane (2 aggs x 8 groups)

typedef __attribute__((ext_vector_type(8))) short short8;
typedef __attribute__((ext_vector_type(4))) float f32x4;

__device__ __forceinline__ unsigned short f2bf(float f) {
  __hip_bfloat16 h = __float2bfloat16(f);
  union { __hip_bfloat16 h; unsigned short u; } cv; cv.h = h; return cv.u;
}
static __device__ __forceinline__ float fsig(float x) { return 1.0f / (1.0f + __expf(-x)); }
static __device__ __forceinline__ float ftanhf(float x) {
  float e = __expf(-2.0f * fabsf(x));
  float t = (1.0f - e) / (1.0f + e);
  return copysignf(t, x);
}

// ---- x [B,T,E] f32 -> xT [T,B,E] bf16 (contiguous 64KB window per step) ----
__global__ __launch_bounds__(256) void transpose_x_kernel(const float* __restrict__ x,
                                                          unsigned short* __restrict__ xT) {
  const int bid = blockIdx.x;          // row*Tt + t
  const int row = bid >> 9, t = bid & (Tt - 1);
  const int e = threadIdx.x * 2;
  const float* src = x + ((size_t)row * Tt + t) * Ee + e;
  float2 v = *(const float2*)src;
  ushort2 o; o.x = f2bf(v.x); o.y = f2bf(v.y);
  *(ushort2*)(xT + ((size_t)t * Bb + row) * Ee + e) = o;
}

// ---- W [1536,4096] f32 -> per-block B-frag-packed bf16 --------------------
__global__ __launch_bounds__(64) void pack_w_kernel(const float* __restrict__ W,
                                                    unsigned short* __restrict__ Wpk) {
  const int fid = blockIdx.x;          // blk*96 + tau*48 + ks
  const int l = threadIdx.x;
  const int blk = fid / 96, rem = fid % 96;
  const int tau = rem / 48, ks = rem % 48;
  const int c = l & 15;
  const int col = (2 * tau + (c >> 3)) * Hh + blk * HIDB + (c & 7);
  const int k0 = ks * 32 + (l >> 4) * 8;
  short8 v;
#pragma unroll
  for (int i = 0; i < 8; i++) v[i] = (short)f2bf(W[(size_t)(k0 + i) * G4 + col]);
  *(short8*)(Wpk + ((size_t)fid * 64 + l) * 8) = v;
}

// ---- zero h buffer 0 + flag/epoch state -----------------------------------
__global__ __launch_bounds__(256) void init_state_kernel(unsigned short* __restrict__ h0,
                                                         int* __restrict__ flg) {
  int i = blockIdx.x * 256 + threadIdx.x;   // grid covers Bb*Hh
  h0[i] = 0;
  if (i < 4 * NBLK * FPAD + 4 * NREP * FPAD) flg[i] = 0;  // flags + epoch lines
}

// ---- persistent LSTM kernel (+ 2 aggregator blocks) -----------------------
__global__ __launch_bounds__(256, 1) void lstm_persist(
    const unsigned short* __restrict__ xT, const unsigned short* __restrict__ Wpk,
    const float* __restrict__ bias,
    unsigned short* __restrict__ hseq,   // Tt buffers, block-major [bc][row][8hid]
    float* __restrict__ h_f32, int* __restrict__ flg) {
  const int bc = blockIdx.x;
  const int tid = threadIdx.x;
  const int wv = tid >> 6, ln = tid & 63;

  int* epoch = flg + 4 * NBLK * FPAD;   // 4 planes x (2 aggs x 8 groups)

  // ---- aggregator blocks (2): per-group min (16 flags) -> group epochs -----
  if (bc >= NBLK) {
    const int ag = bc - NBLK;           // 0 or 1
    int* flgw2 = flg + wv * NBLK * FPAD;
    int* ep = epoch + (wv * NREP + ag * 8) * FPAD;
    const int gidx = ln >> 3;           // this lane's group (8 lanes/group)
    int prevg = 0;
    int cur = 0;
    while (cur < Tt - 1) {
      int a = __hip_atomic_load(flgw2 + (2 * ln) * FPAD,     __ATOMIC_RELAXED, __HIP_MEMORY_SCOPE_AGENT);
      int b = __hip_atomic_load(flgw2 + (2 * ln + 1) * FPAD, __ATOMIC_RELAXED, __HIP_MEMORY_SCOPE_AGENT);
      int m = a < b ? a : b;
      // 8-lane subgroup min = min over this group's 16 producer flags
#pragma unroll
      for (int off = 1; off <= 4; off <<= 1) {
        int o = __shfl_xor(m, off);
        m = o < m ? o : m;
      }
      if ((ln & 7) == 0 && m > prevg) {
        __hip_atomic_store(ep + gidx * FPAD, m, __ATOMIC_RELAXED, __HIP_MEMORY_SCOPE_AGENT);
        prevg = m;
      }
      // full-wave min for loop exit
      int fm = m;
#pragma unroll
      for (int off = 8; off <= 32; off <<= 1) {
        int o = __shfl_xor(fm, off);
        fm = o < fm ? o : fm;
      }
      cur = fm;
    }
    return;
  }

  // ---------------- worker blocks ------------------------------------------
  __shared__ short8 Wl[2 * NKS * 64];       // 96 KiB

  { // one-time: W slice -> LDS (linear 96KB copy)
    const short8* src = (const short8*)Wpk + (size_t)bc * (2 * NKS * 64);
    for (int i = tid; i < 2 * NKS * 64; i += 256) Wl[i] = src[i];
  }

  const int c = ln & 15, kg = ln >> 4;
  const int arow = wv * 16 + c;        // A-frag row = batch index
  const int rbase = wv * 16 + kg * 4;  // D rows (m89 layout: row=(l>>4)*4+r, col=l&15)
  const int hid = bc * HIDB + (c & 7);
  const bool lo = (c < 8);
  const float bi = bias[hid], bj = bias[Hh + hid];
  const float bff = bias[2 * Hh + hid], bo = bias[3 * Hh + hid];
  float cstate[4] = {0.f, 0.f, 0.f, 0.f};

  __syncthreads();                      // W in LDS ready (only barrier in kernel)

  const short8* W0 = Wl;                // tile0 (gates i,j)
  const short8* W1 = Wl + NKS * 64;     // tile1 (gates f,o)

  // x-part W fragments: same LDS addresses every step -> hoist to registers
  short8 wx0[16], wx1[16];
#pragma unroll
  for (int kk = 0; kk < 16; kk++) { wx0[kk] = W0[kk * 64 + ln]; wx1[kk] = W1[kk * 64 + ln]; }

  int* flgw = flg + wv * NBLK * FPAD;   // own wave's flag domain
  int* myslot = flgw + bc * FPAD;
  int* epA = epoch + (wv * NREP) * FPAD;      // agg0 group lines
  int* epB = epoch + (wv * NREP + 8) * FPAD;  // agg1 group lines

  f32x4 xa0, xa1;
  // x-part for t=0
  {
    const unsigned short* xr = xT + ((size_t)0 * Bb + arow) * Ee + kg * 8;
    f32x4 a0 = {0.f,0.f,0.f,0.f}, a1 = {0.f,0.f,0.f,0.f};
#pragma unroll
    for (int kk = 0; kk < 16; kk++) {
      short8 a = *(const short8*)(xr + kk * 32);
      a0 = __builtin_amdgcn_mfma_f32_16x16x32_bf16(a, wx0[kk], a0, 0, 0, 0);
      a1 = __builtin_amdgcn_mfma_f32_16x16x32_bf16(a, wx1[kk], a1, 0, 0, 0);
    }
    xa0 = a0; xa1 = a1;
  }

// pipelined group consumption: polls for g+1 issued BEFORE loads(g) so the
// compiler's in-order counted waits retire polls while h-loads stay in flight.
#define POLLG(G) do {                                                          \
    pe0 = __hip_atomic_load(epA + (G) * FPAD, __ATOMIC_RELAXED, __HIP_MEMORY_SCOPE_AGENT); \
    pe1 = __hip_atomic_load(epB + (G) * FPAD, __ATOMIC_RELAXED, __HIP_MEMORY_SCOPE_AGENT); \
    __builtin_amdgcn_sched_barrier(0x187);                                     \
  } while (0)

#define WAITG(G) do {                                                          \
    while (pe0 < t && pe1 < t) {                                               \
      pe0 = __hip_atomic_load(epA + (G) * FPAD, __ATOMIC_RELAXED, __HIP_MEMORY_SCOPE_AGENT); \
      pe1 = __hip_atomic_load(epB + (G) * FPAD, __ATOMIC_RELAXED, __HIP_MEMORY_SCOPE_AGENT); \
    }                                                                          \
    asm volatile("" ::: "memory");                                             \
  } while (0)

#define LOADG(G) do {                                                          \
    f[4*(G)+0] = *(const short8*)(hr + (4*(G)+0) * 2048);                      \
    f[4*(G)+1] = *(const short8*)(hr + (4*(G)+1) * 2048);                      \
    f[4*(G)+2] = *(const short8*)(hr + (4*(G)+2) * 2048);                      \
    f[4*(G)+3] = *(const short8*)(hr + (4*(G)+3) * 2048);                      \
    __builtin_amdgcn_sched_barrier(0x187);                                     \
  } while (0)

#define MFMAG(G, A0, A1) do {                                                  \
    _Pragma("unroll")                                                          \
    for (int kk = 4*(G); kk < 4*(G)+4; kk++) {                                 \
      A0 = __builtin_amdgcn_mfma_f32_16x16x32_bf16(f[kk], W0[(16+kk)*64+ln], A0, 0, 0, 0); \
      A1 = __builtin_amdgcn_mfma_f32_16x16x32_bf16(f[kk], W1[(16+kk)*64+ln], A1, 0, 0, 0); \
    }                                                                          \
  } while (0)

  for (int t = 0; t < Tt; t++) {
    const unsigned short* hr = hseq + (size_t)t * (NBLK * Bb * HIDB) + kg * 512 + arow * 8;
    short8 f[32];
    f32x4 a0 = xa0, a1 = xa1;
    f32x4 b0 = {0.f,0.f,0.f,0.f}, b1 = {0.f,0.f,0.f,0.f};
    int pe0, pe1;

    POLLG(0);
    WAITG(0); POLLG(1); LOADG(0);
    WAITG(1); POLLG(2); LOADG(1); MFMAG(0, a0, a1);
    WAITG(2); POLLG(3); LOADG(2); MFMAG(1, a0, a1);
    WAITG(3); POLLG(4); LOADG(3); MFMAG(2, a0, a1);
    WAITG(4); POLLG(5); LOADG(4); MFMAG(3, a0, a1);
    WAITG(5); POLLG(6); LOADG(5); MFMAG(4, b0, b1);
    WAITG(6); POLLG(7); LOADG(6); MFMAG(5, b0, b1);
    WAITG(7);           LOADG(7); MFMAG(6, b0, b1);
    MFMAG(7, b0, b1);
    a0 += b0; a1 += b1;                 // join split chains (R16 order)

    if (t < Tt - 1) {
      // ---- cell update with INLINE pack+store: store for row-group r flies
      // while r+1's transcendental chain computes.
      unsigned long long* hob = (unsigned long long*)hseq
                                + (size_t)(t + 1) * (NBLK * Bb * HIDB / 4)
                                + bc * (Bb * HIDB / 4);
#pragma unroll
      for (int r = 0; r < 4; r++) {
        const float p0 = a0[r], p1 = a1[r];
        const float s0 = __shfl_xor(p0, 8), s1 = __shfl_xor(p1, 8);
        const float gi = (lo ? p0 : s0) + bi;
        const float gj = (lo ? s0 : p0) + bj;
        const float gf = (lo ? p1 : s1) + bff;
        const float go = (lo ? s1 : p1) + bo;
        const float cn = cstate[r] * fsig(gf + 1.0f) + fsig(gi) * ftanhf(gj);
        cstate[r] = cn;
        const float hn = ftanhf(cn) * fsig(go);
        unsigned short us = f2bf(hn);
        unsigned short ps = (unsigned short)__shfl_xor((int)us, 1);
        unsigned int hw = (unsigned)us | ((unsigned)ps << 16);
        unsigned int p2 = (unsigned)__shfl_xor((int)hw, 2);
        unsigned long long hq = (unsigned long long)hw | ((unsigned long long)p2 << 32);
        if (lo && !(c & 3))
          __hip_atomic_store(hob + (rbase + r) * 2 + (c >> 2),
                             hq, __ATOMIC_RELAXED, __HIP_MEMORY_SCOPE_AGENT);
      }
      asm volatile("" ::: "memory");    // stores issued above this point
      // ---- x-loads for t+1 issued BEFORE the ack; counted drain acks only
      // the 4 stores (oldest), x-loads keep flying under the flag + x-GEMM.
      const unsigned short* xr = xT + ((size_t)(t + 1) * Bb + arow) * Ee + kg * 8;
      short8 xl[16];
#pragma unroll
      for (int kk = 0; kk < 16; kk++) xl[kk] = *(const short8*)(xr + kk * 32);
      asm volatile("s_waitcnt vmcnt(16)" ::: "memory"); // 4 stores acked
      __builtin_amdgcn_sched_barrier(0x187);
      if (ln == 0)
        __hip_atomic_store(myslot, t + 1, __ATOMIC_RELAXED, __HIP_MEMORY_SCOPE_AGENT);
      // x-part MFMAs for t+1 (W from registers) in the detect shadow
      {
        f32x4 c0 = {0.f,0.f,0.f,0.f}, c1 = {0.f,0.f,0.f,0.f};
#pragma unroll
        for (int kk = 0; kk < 16; kk++) {
          c0 = __builtin_amdgcn_mfma_f32_16x16x32_bf16(xl[kk], wx0[kk], c0, 0, 0, 0);
          c1 = __builtin_amdgcn_mfma_f32_16x16x32_bf16(xl[kk], wx1[kk], c1, 0, 0, 0);
        }
        xa0 = c0; xa1 = c1;
      }
    } else {
      float hnew[4];
#pragma unroll
      for (int r = 0; r < 4; r++) {
        const float p0 = a0[r], p1 = a1[r];
        const float s0 = __shfl_xor(p0, 8), s1 = __shfl_xor(p1, 8);
        const float gi = (lo ? p0 : s0) + bi;
        const float gj = (lo ? s0 : p0) + bj;
        const float gf = (lo ? p1 : s1) + bff;
        const float go = (lo ? s1 : p1) + bo;
        const float cn = cstate[r] * fsig(gf + 1.0f) + fsig(gi) * ftanhf(gj);
        cstate[r] = cn;
        hnew[r] = ftanhf(cn) * fsig(go);
      }
      if (lo) {
#pragma unroll
        for (int r = 0; r < 4; r++) h_f32[(rbase + r) * Hh + hid] = hnew[r];
      }
    }
  }
#undef POLLG
#undef WAITG
#undef LOADG
#undef MFMAG
}

// ---- classifier: pred = h @ outW + outb, softmax, per-row CE --------------
__global__ __launch_bounds__(256) void classifier_kernel(
    const float* __restrict__ h, const float* __restrict__ outW,
    const float* __restrict__ outb, const float* __restrict__ y,
    float* __restrict__ out, float* __restrict__ losses) {
  __shared__ float red[256];
  const int brow = blockIdx.x;
  const int tid = threadIdx.x;
  const int cc = tid & 31;
  const int part = tid >> 5;
  const float* hr = h + brow * Hh;
  float p = 0.f;
  for (int k = part * 128; k < part * 128 + 128; k++)
    p += hr[k] * outW[k * Cc + cc];
  red[tid] = p;
  __syncthreads();
  if (part < 4) red[tid] += red[tid + 128];
  __syncthreads();
  if (part < 2) red[tid] += red[tid + 64];
  __syncthreads();
  if (part < 1) red[tid] += red[tid + 32];
  __syncthreads();
  if (tid < 32) {
    const float logit = red[tid] + outb[tid];
    float m = logit;
    for (int off = 16; off >= 1; off >>= 1) m = fmaxf(m, __shfl_xor(m, off));
    const float e = __expf(logit - m);
    float s = e;
    for (int off = 16; off >= 1; off >>= 1) s += __shfl_xor(s, off);
    out[brow * Cc + tid] = logit;
    out[Bb * Cc + brow * Cc + tid] = e / s;
    const float logp = (logit - m) - __logf(s);
    float contrib = y[brow * Cc + tid] * logp;
    for (int off = 16; off >= 1; off >>= 1) contrib += __shfl_xor(contrib, off);
    if (tid == 0) losses[brow] = -contrib;
  }
}

__global__ __launch_bounds__(64) void finalize_kernel(const float* __restrict__ losses,
                                                      float* __restrict__ out) {
  float v = losses[threadIdx.x];
  for (int off = 32; off >= 1; off >>= 1) v += __shfl_down(v, off);
  if (threadIdx.x == 0) out[2 * Bb * Cc] = v * (1.0f / Bb);
}

extern "C" void kernel_launch(void* const* d_in, const int* in_sizes, int n_in,
                              void* d_out, int out_size, void* d_ws, size_t ws_size,
                              hipStream_t stream) {
  const float* x    = (const float*)d_in[0];
  const float* y    = (const float*)d_in[1];
  // d_in[2] = seqlen (unused)
  const float* W    = (const float*)d_in[3];
  const float* bias = (const float*)d_in[4];
  const float* outW = (const float*)d_in[5];
  const float* outb = (const float*)d_in[6];
  float* out = (float*)d_out;

  char* wsp = (char*)d_ws;
  size_t off = 0;
  auto walloc = [&](size_t bytes) -> void* {
    void* p = wsp + off;
    off += (bytes + 255) & ~(size_t)255;
    return p;
  };
  unsigned short* xT   = (unsigned short*)walloc((size_t)Bb * Tt * Ee * 2);         // 32 MiB
  unsigned short* Wpk  = (unsigned short*)walloc((size_t)NBLK * 2 * NKS * 64 * 16); // 12 MiB
  unsigned short* hseq = (unsigned short*)walloc((size_t)Tt * Bb * Hh * 2);         // 64 MiB rotating h
  float* hf     = (float*)walloc((size_t)Bb * Hh * 4);
  float* losses = (float*)walloc(256);
  int* flg      = (int*)walloc((4 * NBLK * FPAD + 4 * NREP * FPAD) * 4);            // flags + epochs
  (void)ws_size; (void)in_sizes; (void)n_in; (void)out_size;

  transpose_x_kernel<<<Bb * Tt, 256, 0, stream>>>(x, xT);
  pack_w_kernel<<<NBLK * 2 * NKS, 64, 0, stream>>>(W, Wpk);
  init_state_kernel<<<(Bb * Hh) / 256, 256, 0, stream>>>(hseq, flg);

  lstm_persist<<<NBLK + 2, 256, 0, stream>>>(xT, Wpk, bias, hseq, hf, flg);

  classifier_kernel<<<Bb, 256, 0, stream>>>(hf, outW, outb, y, out, losses);
  finalize_kernel<<<1, 64, 0, stream>>>(losses, out);
}

// Round 18
// 2755.104 us; speedup vs baseline: 1.2592x; 1.2592x over previous
//
#include <hip/hip_runtime.h>
#include <hip/hip_bf16.h>

// SentenceClassifier: LSTM(B=64,T=512,E=512,H=1024) -> h_T @ outW + outb -> softmax/CE
// Persistent-kernel, 128 worker blocks x 256 thr + 4 AGGREGATOR blocks.
// R18 = R16 (best, 2717us) with QUAD-PHASE AGGREGATORS: 4 aggregator blocks
// sample the 128 producer flags at independent phases; each publishes a
// full-min epoch to 4 replica lines per plane (16 lines total, as R16).
// Consumers poll one line from each quarter and proceed when ANY >= t (every
// published value is a full min over all 128 flags -> sufficient). Cuts the
// detect sampling quantization roughly in half vs dual aggs; each agg also
// stores only 4 replicas (faster publication). R17's group-granular epochs
// REGRESSED (+28%: per-group waits re-fragmented the h-burst into 8 exposed
// latencies) and are reverted. Everything else R16-verbatim: rotating cold
// h buffers (block-major [bc][row][8hid]); inline cell pack+store (8B agent
// write-through); counted store-ack vmcnt(16) overlapped with t+1 x-loads;
// 4-phase h-burst drain (vmcnt 24/16/8/0) with sched_barrier(0x187); split
// accumulator chains (a/b); x-part W in registers; x-GEMM in detect shadow;
// no __syncthreads in t-loop. absmax must remain exactly 0.125.

#define Bb 64
#define Tt 512
#define Ee 512
#define Hh 1024
#define Cc 32
#define G4 4096
#define NKS 48     // (E+H)/32
#define NBLK 128
#define HIDB 8     // hid units per block
#define FPAD 32    // flag slot pad (ints) = 128B
#define NREP 16    // epoch replica lines per plane (4 aggs x 4)
#define NAGG 4

typedef __attribute__((ext_vector_type(8))) short short8;
typedef __attribute__((ext_vector_type(4))) float f32x4;

__device__ __forceinline__ unsigned short f2bf(float f) {
  __hip_bfloat16 h = __float2bfloat16(f);
  union { __hip_bfloat16 h; unsigned short u; } cv; cv.h = h; return cv.u;
}
static __device__ __forceinline__ float fsig(float x) { return 1.0f / (1.0f + __expf(-x)); }
static __device__ __forceinline__ float ftanhf(float x) {
  float e = __expf(-2.0f * fabsf(x));
  float t = (1.0f - e) / (1.0f + e);
  return copysignf(t, x);
}

// ---- x [B,T,E] f32 -> xT [T,B,E] bf16 (contiguous 64KB window per step) ----
__global__ __launch_bounds__(256) void transpose_x_kernel(const float* __restrict__ x,
                                                          unsigned short* __restrict__ xT) {
  const int bid = blockIdx.x;          // row*Tt + t
  const int row = bid >> 9, t = bid & (Tt - 1);
  const int e = threadIdx.x * 2;
  const float* src = x + ((size_t)row * Tt + t) * Ee + e;
  float2 v = *(const float2*)src;
  ushort2 o; o.x = f2bf(v.x); o.y = f2bf(v.y);
  *(ushort2*)(xT + ((size_t)t * Bb + row) * Ee + e) = o;
}

// ---- W [1536,4096] f32 -> per-block B-frag-packed bf16 --------------------
__global__ __launch_bounds__(64) void pack_w_kernel(const float* __restrict__ W,
                                                    unsigned short* __restrict__ Wpk) {
  const int fid = blockIdx.x;          // blk*96 + tau*48 + ks
  const int l = threadIdx.x;
  const int blk = fid / 96, rem = fid % 96;
  const int tau = rem / 48, ks = rem % 48;
  const int c = l & 15;
  const int col = (2 * tau + (c >> 3)) * Hh + blk * HIDB + (c & 7);
  const int k0 = ks * 32 + (l >> 4) * 8;
  short8 v;
#pragma unroll
  for (int i = 0; i < 8; i++) v[i] = (short)f2bf(W[(size_t)(k0 + i) * G4 + col]);
  *(short8*)(Wpk + ((size_t)fid * 64 + l) * 8) = v;
}

// ---- zero h buffer 0 + flag/epoch state -----------------------------------
__global__ __launch_bounds__(256) void init_state_kernel(unsigned short* __restrict__ h0,
                                                         int* __restrict__ flg) {
  int i = blockIdx.x * 256 + threadIdx.x;   // grid covers Bb*Hh
  h0[i] = 0;
  if (i < 4 * NBLK * FPAD + 4 * NREP * FPAD) flg[i] = 0;  // flags + epoch replicas
}

// ---- persistent LSTM kernel (+ 4 aggregator blocks) -----------------------
__global__ __launch_bounds__(256, 1) void lstm_persist(
    const unsigned short* __restrict__ xT, const unsigned short* __restrict__ Wpk,
    const float* __restrict__ bias,
    unsigned short* __restrict__ hseq,   // Tt buffers, block-major [bc][row][8hid]
    float* __restrict__ h_f32, int* __restrict__ flg) {
  const int bc = blockIdx.x;
  const int tid = threadIdx.x;
  const int wv = tid >> 6, ln = tid & 63;

  int* epoch = flg + 4 * NBLK * FPAD;   // 4 planes x 16 replica lines

  // ------- aggregator blocks (4): min-reduce flags -> replica quarters -----
  if (bc >= NBLK) {
    const int ag = bc - NBLK;           // 0..3
    int* flgw2 = flg + wv * NBLK * FPAD;
    int* ep = epoch + (wv * NREP + ag * 4) * FPAD;
    int cur = 0;
    while (cur < Tt - 1) {
      int a = __hip_atomic_load(flgw2 + ln * FPAD,        __ATOMIC_RELAXED, __HIP_MEMORY_SCOPE_AGENT);
      int b = __hip_atomic_load(flgw2 + (ln + 64) * FPAD, __ATOMIC_RELAXED, __HIP_MEMORY_SCOPE_AGENT);
      int m = a < b ? a : b;
#pragma unroll
      for (int off = 32; off >= 1; off >>= 1) {
        int o = __shfl_xor(m, off);
        m = o < m ? o : m;
      }
      if (m > cur) {
        cur = m;
        if (ln < 4)                     // 4 replica stores in parallel
          __hip_atomic_store(ep + ln * FPAD, cur, __ATOMIC_RELAXED, __HIP_MEMORY_SCOPE_AGENT);
      }
    }
    return;
  }

  // ---------------- worker blocks ------------------------------------------
  __shared__ short8 Wl[2 * NKS * 64];       // 96 KiB

  { // one-time: W slice -> LDS (linear 96KB copy)
    const short8* src = (const short8*)Wpk + (size_t)bc * (2 * NKS * 64);
    for (int i = tid; i < 2 * NKS * 64; i += 256) Wl[i] = src[i];
  }

  const int c = ln & 15, kg = ln >> 4;
  const int arow = wv * 16 + c;        // A-frag row = batch index
  const int rbase = wv * 16 + kg * 4;  // D rows (m89 layout: row=(l>>4)*4+r, col=l&15)
  const int hid = bc * HIDB + (c & 7);
  const bool lo = (c < 8);
  const float bi = bias[hid], bj = bias[Hh + hid];
  const float bff = bias[2 * Hh + hid], bo = bias[3 * Hh + hid];
  float cstate[4] = {0.f, 0.f, 0.f, 0.f};

  __syncthreads();                      // W in LDS ready (only barrier in kernel)

  const short8* W0 = Wl;                // tile0 (gates i,j)
  const short8* W1 = Wl + NKS * 64;     // tile1 (gates f,o)

  // x-part W fragments: same LDS addresses every step -> hoist to registers
  short8 wx0[16], wx1[16];
#pragma unroll
  for (int kk = 0; kk < 16; kk++) { wx0[kk] = W0[kk * 64 + ln]; wx1[kk] = W1[kk * 64 + ln]; }

  int* flgw = flg + wv * NBLK * FPAD;   // own wave's flag domain
  int* myslot = flgw + bc * FPAD;
  // one replica line from each aggregator quarter; proceed when ANY reaches t
  int* myep0 = epoch + (wv * NREP +  0 + (bc & 3)) * FPAD;
  int* myep1 = epoch + (wv * NREP +  4 + (bc & 3)) * FPAD;
  int* myep2 = epoch + (wv * NREP +  8 + (bc & 3)) * FPAD;
  int* myep3 = epoch + (wv * NREP + 12 + (bc & 3)) * FPAD;

  f32x4 xa0, xa1;
  // x-part for t=0
  {
    const unsigned short* xr = xT + ((size_t)0 * Bb + arow) * Ee + kg * 8;
    f32x4 a0 = {0.f,0.f,0.f,0.f}, a1 = {0.f,0.f,0.f,0.f};
#pragma unroll
    for (int kk = 0; kk < 16; kk++) {
      short8 a = *(const short8*)(xr + kk * 32);
      a0 = __builtin_amdgcn_mfma_f32_16x16x32_bf16(a, wx0[kk], a0, 0, 0, 0);
      a1 = __builtin_amdgcn_mfma_f32_16x16x32_bf16(a, wx1[kk], a1, 0, 0, 0);
    }
    xa0 = a0; xa1 = a1;
  }

  for (int t = 0; t < Tt; t++) {
    // ---- detect: any of 4 replica lines (quad aggregators out of phase)
    for (;;) {
      int e0 = __hip_atomic_load(myep0, __ATOMIC_RELAXED, __HIP_MEMORY_SCOPE_AGENT);
      int e1 = __hip_atomic_load(myep1, __ATOMIC_RELAXED, __HIP_MEMORY_SCOPE_AGENT);
      int e2 = __hip_atomic_load(myep2, __ATOMIC_RELAXED, __HIP_MEMORY_SCOPE_AGENT);
      int e3 = __hip_atomic_load(myep3, __ATOMIC_RELAXED, __HIP_MEMORY_SCOPE_AGENT);
      if (e0 >= t || e1 >= t || e2 >= t || e3 >= t) break;
    }
    asm volatile("" ::: "memory");      // no hoist of h loads above the wait

    // ---- forced burst, 4-phase drain: issue all 32 16B loads; MFMA 8 at a
    // time as loads retire. Split accumulators (a/b pairs) double chain ILP.
    const unsigned short* hr = hseq + (size_t)t * (NBLK * Bb * HIDB) + kg * 512 + arow * 8;
    short8 f[32];
#pragma unroll
    for (int kk = 0; kk < 32; kk++) f[kk] = *(const short8*)(hr + kk * 2048);

    f32x4 a0 = xa0, a1 = xa1;
    f32x4 b0 = {0.f,0.f,0.f,0.f}, b1 = {0.f,0.f,0.f,0.f};
    asm volatile("s_waitcnt vmcnt(24)" ::: "memory");   // f[0..7] landed
    __builtin_amdgcn_sched_barrier(0x187);
#pragma unroll
    for (int kk = 0; kk < 8; kk++) {
      a0 = __builtin_amdgcn_mfma_f32_16x16x32_bf16(f[kk], W0[(16 + kk) * 64 + ln], a0, 0, 0, 0);
      a1 = __builtin_amdgcn_mfma_f32_16x16x32_bf16(f[kk], W1[(16 + kk) * 64 + ln], a1, 0, 0, 0);
    }
    asm volatile("s_waitcnt vmcnt(16)" ::: "memory");   // f[8..15]
    __builtin_amdgcn_sched_barrier(0x187);
#pragma unroll
    for (int kk = 8; kk < 16; kk++) {
      a0 = __builtin_amdgcn_mfma_f32_16x16x32_bf16(f[kk], W0[(16 + kk) * 64 + ln], a0, 0, 0, 0);
      a1 = __builtin_amdgcn_mfma_f32_16x16x32_bf16(f[kk], W1[(16 + kk) * 64 + ln], a1, 0, 0, 0);
    }
    asm volatile("s_waitcnt vmcnt(8)" ::: "memory");    // f[16..23]
    __builtin_amdgcn_sched_barrier(0x187);
#pragma unroll
    for (int kk = 16; kk < 24; kk++) {
      b0 = __builtin_amdgcn_mfma_f32_16x16x32_bf16(f[kk], W0[(16 + kk) * 64 + ln], b0, 0, 0, 0);
      b1 = __builtin_amdgcn_mfma_f32_16x16x32_bf16(f[kk], W1[(16 + kk) * 64 + ln], b1, 0, 0, 0);
    }
    asm volatile("s_waitcnt vmcnt(0)" ::: "memory");    // f[24..31]
    __builtin_amdgcn_sched_barrier(0x187);
#pragma unroll
    for (int kk = 24; kk < 32; kk++) {
      b0 = __builtin_amdgcn_mfma_f32_16x16x32_bf16(f[kk], W0[(16 + kk) * 64 + ln], b0, 0, 0, 0);
      b1 = __builtin_amdgcn_mfma_f32_16x16x32_bf16(f[kk], W1[(16 + kk) * 64 + ln], b1, 0, 0, 0);
    }
    a0 += b0; a1 += b1;                 // join split chains

    if (t < Tt - 1) {
      // ---- cell update with INLINE pack+store: store for row-group r flies
      // while r+1's transcendental chain computes. vmcnt clean at entry
      // (burst fully drained above) -> exactly 4 store instrs outstanding.
      unsigned long long* hob = (unsigned long long*)hseq
                                + (size_t)(t + 1) * (NBLK * Bb * HIDB / 4)
                                + bc * (Bb * HIDB / 4);
#pragma unroll
      for (int r = 0; r < 4; r++) {
        const float p0 = a0[r], p1 = a1[r];
        const float s0 = __shfl_xor(p0, 8), s1 = __shfl_xor(p1, 8);
        const float gi = (lo ? p0 : s0) + bi;
        const float gj = (lo ? s0 : p0) + bj;
        const float gf = (lo ? p1 : s1) + bff;
        const float go = (lo ? s1 : p1) + bo;
        const float cn = cstate[r] * fsig(gf + 1.0f) + fsig(gi) * ftanhf(gj);
        cstate[r] = cn;
        const float hn = ftanhf(cn) * fsig(go);
        unsigned short us = f2bf(hn);
        unsigned short ps = (unsigned short)__shfl_xor((int)us, 1);
        unsigned int hw = (unsigned)us | ((unsigned)ps << 16);
        unsigned int p2 = (unsigned)__shfl_xor((int)hw, 2);
        unsigned long long hq = (unsigned long long)hw | ((unsigned long long)p2 << 32);
        if (lo && !(c & 3))
          __hip_atomic_store(hob + (rbase + r) * 2 + (c >> 2),
                             hq, __ATOMIC_RELAXED, __HIP_MEMORY_SCOPE_AGENT);
      }
      asm volatile("" ::: "memory");    // stores issued above this point
      // ---- x-loads for t+1 issued BEFORE the ack; counted drain acks only
      // the 4 stores (oldest), x-loads keep flying under the flag + x-GEMM.
      const unsigned short* xr = xT + ((size_t)(t + 1) * Bb + arow) * Ee + kg * 8;
      short8 xl[16];
#pragma unroll
      for (int kk = 0; kk < 16; kk++) xl[kk] = *(const short8*)(xr + kk * 32);
      asm volatile("s_waitcnt vmcnt(16)" ::: "memory"); // 4 stores acked
      __builtin_amdgcn_sched_barrier(0x187);
      if (ln == 0)
        __hip_atomic_store(myslot, t + 1, __ATOMIC_RELAXED, __HIP_MEMORY_SCOPE_AGENT);
      // x-part MFMAs for t+1 (W from registers) in the detect shadow
      {
        f32x4 c0 = {0.f,0.f,0.f,0.f}, c1 = {0.f,0.f,0.f,0.f};
#pragma unroll
        for (int kk = 0; kk < 16; kk++) {
          c0 = __builtin_amdgcn_mfma_f32_16x16x32_bf16(xl[kk], wx0[kk], c0, 0, 0, 0);
          c1 = __builtin_amdgcn_mfma_f32_16x16x32_bf16(xl[kk], wx1[kk], c1, 0, 0, 0);
        }
        xa0 = c0; xa1 = c1;
      }
    } else {
      float hnew[4];
#pragma unroll
      for (int r = 0; r < 4; r++) {
        const float p0 = a0[r], p1 = a1[r];
        const float s0 = __shfl_xor(p0, 8), s1 = __shfl_xor(p1, 8);
        const float gi = (lo ? p0 : s0) + bi;
        const float gj = (lo ? s0 : p0) + bj;
        const float gf = (lo ? p1 : s1) + bff;
        const float go = (lo ? s1 : p1) + bo;
        const float cn = cstate[r] * fsig(gf + 1.0f) + fsig(gi) * ftanhf(gj);
        cstate[r] = cn;
        hnew[r] = ftanhf(cn) * fsig(go);
      }
      if (lo) {
#pragma unroll
        for (int r = 0; r < 4; r++) h_f32[(rbase + r) * Hh + hid] = hnew[r];
      }
    }
  }
}

// ---- classifier: pred = h @ outW + outb, softmax, per-row CE --------------
__global__ __launch_bounds__(256) void classifier_kernel(
    const float* __restrict__ h, const float* __restrict__ outW,
    const float* __restrict__ outb, const float* __restrict__ y,
    float* __restrict__ out, float* __restrict__ losses) {
  __shared__ float red[256];
  const int brow = blockIdx.x;
  const int tid = threadIdx.x;
  const int cc = tid & 31;
  const int part = tid >> 5;
  const float* hr = h + brow * Hh;
  float p = 0.f;
  for (int k = part * 128; k < part * 128 + 128; k++)
    p += hr[k] * outW[k * Cc + cc];
  red[tid] = p;
  __syncthreads();
  if (part < 4) red[tid] += red[tid + 128];
  __syncthreads();
  if (part < 2) red[tid] += red[tid + 64];
  __syncthreads();
  if (part < 1) red[tid] += red[tid + 32];
  __syncthreads();
  if (tid < 32) {
    const float logit = red[tid] + outb[tid];
    float m = logit;
    for (int off = 16; off >= 1; off >>= 1) m = fmaxf(m, __shfl_xor(m, off));
    const float e = __expf(logit - m);
    float s = e;
    for (int off = 16; off >= 1; off >>= 1) s += __shfl_xor(s, off);
    out[brow * Cc + tid] = logit;
    out[Bb * Cc + brow * Cc + tid] = e / s;
    const float logp = (logit - m) - __logf(s);
    float contrib = y[brow * Cc + tid] * logp;
    for (int off = 16; off >= 1; off >>= 1) contrib += __shfl_xor(contrib, off);
    if (tid == 0) losses[brow] = -contrib;
  }
}

__global__ __launch_bounds__(64) void finalize_kernel(const float* __restrict__ losses,
                                                      float* __restrict__ out) {
  float v = losses[threadIdx.x];
  for (int off = 32; off >= 1; off >>= 1) v += __shfl_down(v, off);
  if (threadIdx.x == 0) out[2 * Bb * Cc] = v * (1.0f / Bb);
}

extern "C" void kernel_launch(void* const* d_in, const int* in_sizes, int n_in,
                              void* d_out, int out_size, void* d_ws, size_t ws_size,
                              hipStream_t stream) {
  const float* x    = (const float*)d_in[0];
  const float* y    = (const float*)d_in[1];
  // d_in[2] = seqlen (unused)
  const float* W    = (const float*)d_in[3];
  const float* bias = (const float*)d_in[4];
  const float* outW = (const float*)d_in[5];
  const float* outb = (const float*)d_in[6];
  float* out = (float*)d_out;

  char* wsp = (char*)d_ws;
  size_t off = 0;
  auto walloc = [&](size_t bytes) -> void* {
    void* p = wsp + off;
    off += (bytes + 255) & ~(size_t)255;
    return p;
  };
  unsigned short* xT   = (unsigned short*)walloc((size_t)Bb * Tt * Ee * 2);         // 32 MiB
  unsigned short* Wpk  = (unsigned short*)walloc((size_t)NBLK * 2 * NKS * 64 * 16); // 12 MiB
  unsigned short* hseq = (unsigned short*)walloc((size_t)Tt * Bb * Hh * 2);         // 64 MiB rotating h
  float* hf     = (float*)walloc((size_t)Bb * Hh * 4);
  float* losses = (float*)walloc(256);
  int* flg      = (int*)walloc((4 * NBLK * FPAD + 4 * NREP * FPAD) * 4);            // flags + epochs
  (void)ws_size; (void)in_sizes; (void)n_in; (void)out_size;

  transpose_x_kernel<<<Bb * Tt, 256, 0, stream>>>(x, xT);
  pack_w_kernel<<<NBLK * 2 * NKS, 64, 0, stream>>>(W, Wpk);
  init_state_kernel<<<(Bb * Hh) / 256, 256, 0, stream>>>(hseq, flg);

  lstm_persist<<<NBLK + NAGG, 256, 0, stream>>>(xT, Wpk, bias, hseq, hf, flg);

  classifier_kernel<<<Bb, 256, 0, stream>>>(hf, outW, outb, y, out, losses);
  finalize_kernel<<<1, 64, 0, stream>>>(losses, out);
}

// Round 19
// 2725.560 us; speedup vs baseline: 1.2729x; 1.0108x over previous
//
#include <hip/hip_runtime.h>
#include <hip/hip_bf16.h>

// SentenceClassifier: LSTM(B=64,T=512,E=512,H=1024) -> h_T @ outW + outb -> softmax/CE
// Persistent-kernel, 128 worker blocks x 256 thr + 2 AGGREGATOR blocks.
// FINAL (R16 restore, verified 2717us = best of 18 rounds; R17 group-epochs
// +28% regress, R18 quad-aggs null confirmed detect-sampling exhausted).
// Structure: rotating cold h buffers (one 128KB buffer/step, block-major
// [bc][row][8hid]) -- producers store agent-scope write-through 8B words
// inline in the cell r-loop; counted store-ack (vmcnt(16)) overlapped with
// t+1 x-loads; flag -> dual phase-diverse aggregator min-reduce -> 16 epoch
// replica lines; consumers poll 2 replicas (either >= t suffices); forced
// 32x16B h-load burst with 4-phase counted drain (vmcnt 24/16/8/0) and
// sched_barrier(0x187) (ALU|VALU|SALU|DS cross, MFMA+VMEM pinned); split
// accumulator chains (a/b, joined once); x-part W in 128 registers; x-GEMM
// in the detect shadow; no __syncthreads in the t-loop.
// Step period 5.3us = loop-carried chain floor: cell -> store-ack RT ->
// flag RT -> agg sample -> detect -> HBM h-fill -> GEMM (+ max-of-128 skew).

#define Bb 64
#define Tt 512
#define Ee 512
#define Hh 1024
#define Cc 32
#define G4 4096
#define NKS 48     // (E+H)/32
#define NBLK 128
#define HIDB 8     // hid units per block
#define FPAD 32    // flag slot pad (ints) = 128B
#define NREP 16    // epoch replicas per plane (8 per aggregator)

typedef __attribute__((ext_vector_type(8))) short short8;
typedef __attribute__((ext_vector_type(4))) float f32x4;

__device__ __forceinline__ unsigned short f2bf(float f) {
  __hip_bfloat16 h = __float2bfloat16(f);
  union { __hip_bfloat16 h; unsigned short u; } cv; cv.h = h; return cv.u;
}
static __device__ __forceinline__ float fsig(float x) { return 1.0f / (1.0f + __expf(-x)); }
static __device__ __forceinline__ float ftanhf(float x) {
  float e = __expf(-2.0f * fabsf(x));
  float t = (1.0f - e) / (1.0f + e);
  return copysignf(t, x);
}

// ---- x [B,T,E] f32 -> xT [T,B,E] bf16 (contiguous 64KB window per step) ----
__global__ __launch_bounds__(256) void transpose_x_kernel(const float* __restrict__ x,
                                                          unsigned short* __restrict__ xT) {
  const int bid = blockIdx.x;          // row*Tt + t
  const int row = bid >> 9, t = bid & (Tt - 1);
  const int e = threadIdx.x * 2;
  const float* src = x + ((size_t)row * Tt + t) * Ee + e;
  float2 v = *(const float2*)src;
  ushort2 o; o.x = f2bf(v.x); o.y = f2bf(v.y);
  *(ushort2*)(xT + ((size_t)t * Bb + row) * Ee + e) = o;
}

// ---- W [1536,4096] f32 -> per-block B-frag-packed bf16 --------------------
__global__ __launch_bounds__(64) void pack_w_kernel(const float* __restrict__ W,
                                                    unsigned short* __restrict__ Wpk) {
  const int fid = blockIdx.x;          // blk*96 + tau*48 + ks
  const int l = threadIdx.x;
  const int blk = fid / 96, rem = fid % 96;
  const int tau = rem / 48, ks = rem % 48;
  const int c = l & 15;
  const int col = (2 * tau + (c >> 3)) * Hh + blk * HIDB + (c & 7);
  const int k0 = ks * 32 + (l >> 4) * 8;
  short8 v;
#pragma unroll
  for (int i = 0; i < 8; i++) v[i] = (short)f2bf(W[(size_t)(k0 + i) * G4 + col]);
  *(short8*)(Wpk + ((size_t)fid * 64 + l) * 8) = v;
}

// ---- zero h buffer 0 + flag/epoch state -----------------------------------
__global__ __launch_bounds__(256) void init_state_kernel(unsigned short* __restrict__ h0,
                                                         int* __restrict__ flg) {
  int i = blockIdx.x * 256 + threadIdx.x;   // grid covers Bb*Hh
  h0[i] = 0;
  if (i < 4 * NBLK * FPAD + 4 * NREP * FPAD) flg[i] = 0;  // flags + epoch replicas
}

// ---- persistent LSTM kernel (+ 2 aggregator blocks) -----------------------
__global__ __launch_bounds__(256, 1) void lstm_persist(
    const unsigned short* __restrict__ xT, const unsigned short* __restrict__ Wpk,
    const float* __restrict__ bias,
    unsigned short* __restrict__ hseq,   // Tt buffers, block-major [bc][row][8hid]
    float* __restrict__ h_f32, int* __restrict__ flg) {
  const int bc = blockIdx.x;
  const int tid = threadIdx.x;
  const int wv = tid >> 6, ln = tid & 63;

  int* epoch = flg + 4 * NBLK * FPAD;   // 4 planes x 16 replica lines

  // ------- aggregator blocks (2): min-reduce flags -> replica halves -------
  if (bc >= NBLK) {
    const int ag = bc - NBLK;           // 0 or 1
    int* flgw2 = flg + wv * NBLK * FPAD;
    int* ep = epoch + (wv * NREP + ag * 8) * FPAD;
    int cur = 0;
    while (cur < Tt - 1) {
      int a = __hip_atomic_load(flgw2 + ln * FPAD,        __ATOMIC_RELAXED, __HIP_MEMORY_SCOPE_AGENT);
      int b = __hip_atomic_load(flgw2 + (ln + 64) * FPAD, __ATOMIC_RELAXED, __HIP_MEMORY_SCOPE_AGENT);
      int m = a < b ? a : b;
#pragma unroll
      for (int off = 32; off >= 1; off >>= 1) {
        int o = __shfl_xor(m, off);
        m = o < m ? o : m;
      }
      if (m > cur) {
        cur = m;
        if (ln < 8)                     // 8 replica stores in parallel
          __hip_atomic_store(ep + ln * FPAD, cur, __ATOMIC_RELAXED, __HIP_MEMORY_SCOPE_AGENT);
      }
    }
    return;
  }

  // ---------------- worker blocks ------------------------------------------
  __shared__ short8 Wl[2 * NKS * 64];       // 96 KiB

  { // one-time: W slice -> LDS (linear 96KB copy)
    const short8* src = (const short8*)Wpk + (size_t)bc * (2 * NKS * 64);
    for (int i = tid; i < 2 * NKS * 64; i += 256) Wl[i] = src[i];
  }

  const int c = ln & 15, kg = ln >> 4;
  const int arow = wv * 16 + c;        // A-frag row = batch index
  const int rbase = wv * 16 + kg * 4;  // D rows (m89 layout: row=(l>>4)*4+r, col=l&15)
  const int hid = bc * HIDB + (c & 7);
  const bool lo = (c < 8);
  const float bi = bias[hid], bj = bias[Hh + hid];
  const float bff = bias[2 * Hh + hid], bo = bias[3 * Hh + hid];
  float cstate[4] = {0.f, 0.f, 0.f, 0.f};

  __syncthreads();                      // W in LDS ready (only barrier in kernel)

  const short8* W0 = Wl;                // tile0 (gates i,j)
  const short8* W1 = Wl + NKS * 64;     // tile1 (gates f,o)

  // x-part W fragments: same LDS addresses every step -> hoist to registers
  short8 wx0[16], wx1[16];
#pragma unroll
  for (int kk = 0; kk < 16; kk++) { wx0[kk] = W0[kk * 64 + ln]; wx1[kk] = W1[kk * 64 + ln]; }

  int* flgw = flg + wv * NBLK * FPAD;   // own wave's flag domain
  int* myslot = flgw + bc * FPAD;
  // one replica from each aggregator's half; proceed when EITHER reaches t
  int* myep0 = epoch + (wv * NREP + (bc & 7)) * FPAD;
  int* myep1 = epoch + (wv * NREP + 8 + (bc & 7)) * FPAD;

  f32x4 xa0, xa1;
  // x-part for t=0
  {
    const unsigned short* xr = xT + ((size_t)0 * Bb + arow) * Ee + kg * 8;
    f32x4 a0 = {0.f,0.f,0.f,0.f}, a1 = {0.f,0.f,0.f,0.f};
#pragma unroll
    for (int kk = 0; kk < 16; kk++) {
      short8 a = *(const short8*)(xr + kk * 32);
      a0 = __builtin_amdgcn_mfma_f32_16x16x32_bf16(a, wx0[kk], a0, 0, 0, 0);
      a1 = __builtin_amdgcn_mfma_f32_16x16x32_bf16(a, wx1[kk], a1, 0, 0, 0);
    }
    xa0 = a0; xa1 = a1;
  }

  for (int t = 0; t < Tt; t++) {
    // ---- detect: either replica (dual aggregators sample out of phase)
    for (;;) {
      int e0 = __hip_atomic_load(myep0, __ATOMIC_RELAXED, __HIP_MEMORY_SCOPE_AGENT);
      int e1 = __hip_atomic_load(myep1, __ATOMIC_RELAXED, __HIP_MEMORY_SCOPE_AGENT);
      if (e0 >= t || e1 >= t) break;
    }
    asm volatile("" ::: "memory");      // no hoist of h loads above the wait

    // ---- forced burst, 4-phase drain: issue all 32 16B loads; MFMA 8 at a
    // time as loads retire. Split accumulators (a/b pairs) double chain ILP.
    const unsigned short* hr = hseq + (size_t)t * (NBLK * Bb * HIDB) + kg * 512 + arow * 8;
    short8 f[32];
#pragma unroll
    for (int kk = 0; kk < 32; kk++) f[kk] = *(const short8*)(hr + kk * 2048);

    f32x4 a0 = xa0, a1 = xa1;
    f32x4 b0 = {0.f,0.f,0.f,0.f}, b1 = {0.f,0.f,0.f,0.f};
    asm volatile("s_waitcnt vmcnt(24)" ::: "memory");   // f[0..7] landed
    __builtin_amdgcn_sched_barrier(0x187);
#pragma unroll
    for (int kk = 0; kk < 8; kk++) {
      a0 = __builtin_amdgcn_mfma_f32_16x16x32_bf16(f[kk], W0[(16 + kk) * 64 + ln], a0, 0, 0, 0);
      a1 = __builtin_amdgcn_mfma_f32_16x16x32_bf16(f[kk], W1[(16 + kk) * 64 + ln], a1, 0, 0, 0);
    }
    asm volatile("s_waitcnt vmcnt(16)" ::: "memory");   // f[8..15]
    __builtin_amdgcn_sched_barrier(0x187);
#pragma unroll
    for (int kk = 8; kk < 16; kk++) {
      a0 = __builtin_amdgcn_mfma_f32_16x16x32_bf16(f[kk], W0[(16 + kk) * 64 + ln], a0, 0, 0, 0);
      a1 = __builtin_amdgcn_mfma_f32_16x16x32_bf16(f[kk], W1[(16 + kk) * 64 + ln], a1, 0, 0, 0);
    }
    asm volatile("s_waitcnt vmcnt(8)" ::: "memory");    // f[16..23]
    __builtin_amdgcn_sched_barrier(0x187);
#pragma unroll
    for (int kk = 16; kk < 24; kk++) {
      b0 = __builtin_amdgcn_mfma_f32_16x16x32_bf16(f[kk], W0[(16 + kk) * 64 + ln], b0, 0, 0, 0);
      b1 = __builtin_amdgcn_mfma_f32_16x16x32_bf16(f[kk], W1[(16 + kk) * 64 + ln], b1, 0, 0, 0);
    }
    asm volatile("s_waitcnt vmcnt(0)" ::: "memory");    // f[24..31]
    __builtin_amdgcn_sched_barrier(0x187);
#pragma unroll
    for (int kk = 24; kk < 32; kk++) {
      b0 = __builtin_amdgcn_mfma_f32_16x16x32_bf16(f[kk], W0[(16 + kk) * 64 + ln], b0, 0, 0, 0);
      b1 = __builtin_amdgcn_mfma_f32_16x16x32_bf16(f[kk], W1[(16 + kk) * 64 + ln], b1, 0, 0, 0);
    }
    a0 += b0; a1 += b1;                 // join split chains

    if (t < Tt - 1) {
      // ---- cell update with INLINE pack+store: store for row-group r flies
      // while r+1's transcendental chain computes. vmcnt clean at entry
      // (burst fully drained above) -> exactly 4 store instrs outstanding.
      unsigned long long* hob = (unsigned long long*)hseq
                                + (size_t)(t + 1) * (NBLK * Bb * HIDB / 4)
                                + bc * (Bb * HIDB / 4);
#pragma unroll
      for (int r = 0; r < 4; r++) {
        const float p0 = a0[r], p1 = a1[r];
        const float s0 = __shfl_xor(p0, 8), s1 = __shfl_xor(p1, 8);
        const float gi = (lo ? p0 : s0) + bi;
        const float gj = (lo ? s0 : p0) + bj;
        const float gf = (lo ? p1 : s1) + bff;
        const float go = (lo ? s1 : p1) + bo;
        const float cn = cstate[r] * fsig(gf + 1.0f) + fsig(gi) * ftanhf(gj);
        cstate[r] = cn;
        const float hn = ftanhf(cn) * fsig(go);
        unsigned short us = f2bf(hn);
        unsigned short ps = (unsigned short)__shfl_xor((int)us, 1);
        unsigned int hw = (unsigned)us | ((unsigned)ps << 16);
        unsigned int p2 = (unsigned)__shfl_xor((int)hw, 2);
        unsigned long long hq = (unsigned long long)hw | ((unsigned long long)p2 << 32);
        if (lo && !(c & 3))
          __hip_atomic_store(hob + (rbase + r) * 2 + (c >> 2),
                             hq, __ATOMIC_RELAXED, __HIP_MEMORY_SCOPE_AGENT);
      }
      asm volatile("" ::: "memory");    // stores issued above this point
      // ---- x-loads for t+1 issued BEFORE the ack; counted drain acks only
      // the 4 stores (oldest), x-loads keep flying under the flag + x-GEMM.
      const unsigned short* xr = xT + ((size_t)(t + 1) * Bb + arow) * Ee + kg * 8;
      short8 xl[16];
#pragma unroll
      for (int kk = 0; kk < 16; kk++) xl[kk] = *(const short8*)(xr + kk * 32);
      asm volatile("s_waitcnt vmcnt(16)" ::: "memory"); // 4 stores acked
      __builtin_amdgcn_sched_barrier(0x187);
      if (ln == 0)
        __hip_atomic_store(myslot, t + 1, __ATOMIC_RELAXED, __HIP_MEMORY_SCOPE_AGENT);
      // x-part MFMAs for t+1 (W from registers) in the detect shadow
      {
        f32x4 c0 = {0.f,0.f,0.f,0.f}, c1 = {0.f,0.f,0.f,0.f};
#pragma unroll
        for (int kk = 0; kk < 16; kk++) {
          c0 = __builtin_amdgcn_mfma_f32_16x16x32_bf16(xl[kk], wx0[kk], c0, 0, 0, 0);
          c1 = __builtin_amdgcn_mfma_f32_16x16x32_bf16(xl[kk], wx1[kk], c1, 0, 0, 0);
        }
        xa0 = c0; xa1 = c1;
      }
    } else {
      float hnew[4];
#pragma unroll
      for (int r = 0; r < 4; r++) {
        const float p0 = a0[r], p1 = a1[r];
        const float s0 = __shfl_xor(p0, 8), s1 = __shfl_xor(p1, 8);
        const float gi = (lo ? p0 : s0) + bi;
        const float gj = (lo ? s0 : p0) + bj;
        const float gf = (lo ? p1 : s1) + bff;
        const float go = (lo ? s1 : p1) + bo;
        const float cn = cstate[r] * fsig(gf + 1.0f) + fsig(gi) * ftanhf(gj);
        cstate[r] = cn;
        hnew[r] = ftanhf(cn) * fsig(go);
      }
      if (lo) {
#pragma unroll
        for (int r = 0; r < 4; r++) h_f32[(rbase + r) * Hh + hid] = hnew[r];
      }
    }
  }
}

// ---- classifier: pred = h @ outW + outb, softmax, per-row CE --------------
__global__ __launch_bounds__(256) void classifier_kernel(
    const float* __restrict__ h, const float* __restrict__ outW,
    const float* __restrict__ outb, const float* __restrict__ y,
    float* __restrict__ out, float* __restrict__ losses) {
  __shared__ float red[256];
  const int brow = blockIdx.x;
  const int tid = threadIdx.x;
  const int cc = tid & 31;
  const int part = tid >> 5;
  const float* hr = h + brow * Hh;
  float p = 0.f;
  for (int k = part * 128; k < part * 128 + 128; k++)
    p += hr[k] * outW[k * Cc + cc];
  red[tid] = p;
  __syncthreads();
  if (part < 4) red[tid] += red[tid + 128];
  __syncthreads();
  if (part < 2) red[tid] += red[tid + 64];
  __syncthreads();
  if (part < 1) red[tid] += red[tid + 32];
  __syncthreads();
  if (tid < 32) {
    const float logit = red[tid] + outb[tid];
    float m = logit;
    for (int off = 16; off >= 1; off >>= 1) m = fmaxf(m, __shfl_xor(m, off));
    const float e = __expf(logit - m);
    float s = e;
    for (int off = 16; off >= 1; off >>= 1) s += __shfl_xor(s, off);
    out[brow * Cc + tid] = logit;
    out[Bb * Cc + brow * Cc + tid] = e / s;
    const float logp = (logit - m) - __logf(s);
    float contrib = y[brow * Cc + tid] * logp;
    for (int off = 16; off >= 1; off >>= 1) contrib += __shfl_xor(contrib, off);
    if (tid == 0) losses[brow] = -contrib;
  }
}

__global__ __launch_bounds__(64) void finalize_kernel(const float* __restrict__ losses,
                                                      float* __restrict__ out) {
  float v = losses[threadIdx.x];
  for (int off = 32; off >= 1; off >>= 1) v += __shfl_down(v, off);
  if (threadIdx.x == 0) out[2 * Bb * Cc] = v * (1.0f / Bb);
}

extern "C" void kernel_launch(void* const* d_in, const int* in_sizes, int n_in,
                              void* d_out, int out_size, void* d_ws, size_t ws_size,
                              hipStream_t stream) {
  const float* x    = (const float*)d_in[0];
  const float* y    = (const float*)d_in[1];
  // d_in[2] = seqlen (unused)
  const float* W    = (const float*)d_in[3];
  const float* bias = (const float*)d_in[4];
  const float* outW = (const float*)d_in[5];
  const float* outb = (const float*)d_in[6];
  float* out = (float*)d_out;

  char* wsp = (char*)d_ws;
  size_t off = 0;
  auto walloc = [&](size_t bytes) -> void* {
    void* p = wsp + off;
    off += (bytes + 255) & ~(size_t)255;
    return p;
  };
  unsigned short* xT   = (unsigned short*)walloc((size_t)Bb * Tt * Ee * 2);         // 32 MiB
  unsigned short* Wpk  = (unsigned short*)walloc((size_t)NBLK * 2 * NKS * 64 * 16); // 12 MiB
  unsigned short* hseq = (unsigned short*)walloc((size_t)Tt * Bb * Hh * 2);         // 64 MiB rotating h
  float* hf     = (float*)walloc((size_t)Bb * Hh * 4);
  float* losses = (float*)walloc(256);
  int* flg      = (int*)walloc((4 * NBLK * FPAD + 4 * NREP * FPAD) * 4);            // flags + epochs
  (void)ws_size; (void)in_sizes; (void)n_in; (void)out_size;

  transpose_x_kernel<<<Bb * Tt, 256, 0, stream>>>(x, xT);
  pack_w_kernel<<<NBLK * 2 * NKS, 64, 0, stream>>>(W, Wpk);
  init_state_kernel<<<(Bb * Hh) / 256, 256, 0, stream>>>(hseq, flg);

  lstm_persist<<<NBLK + 2, 256, 0, stream>>>(xT, Wpk, bias, hseq, hf, flg);

  classifier_kernel<<<Bb, 256, 0, stream>>>(hf, outW, outb, y, out, losses);
  finalize_kernel<<<1, 64, 0, stream>>>(losses, out);
}